// Round 19
// baseline (873.015 us; speedup 1.0000x reference)
//
#include <hip/hip_runtime.h>
#include <math.h>

#define LL   2048
#define BB   8
#define CC   32
#define CHH  256
#define HH   8
#define DD   6

typedef _Float16 h8 __attribute__((ext_vector_type(8)));
typedef _Float16 h4 __attribute__((ext_vector_type(4)));
typedef float f4 __attribute__((ext_vector_type(4)));
typedef float f2v __attribute__((ext_vector_type(2)));

__device__ __forceinline__ void norm_params(const float* st, const float* g,
    const float* bt, int bc, int c, float& scr, float& shr) {
  float s0 = st[bc * 2], s1 = st[bc * 2 + 1];
  float mean = s0 * (1.f / LL);
  float var  = s1 * (1.f / LL) - mean * mean;
  float q = rsqrtf(var + 1e-5f) * g[c];
  scr = q; shr = bt[c] - mean * q;
}

// ---------------------------------------------------------------- encoder
__global__ __launch_bounds__(256) void k_enc(const float* __restrict__ x,
    const float* __restrict__ W, const float* __restrict__ bias,
    float* __restrict__ X) {
  int idx = blockIdx.x * 256 + threadIdx.x;          // B*32*L = 524288
  int l = idx & (LL - 1);
  int c = (idx >> 11) & 31;
  int b = idx >> 16;
  float s = bias[c];
#pragma unroll
  for (int i = 0; i < 6; ++i)
    s = fmaf(W[c * 6 + i], x[((size_t)b * 6 + i) * LL + l], s);
  X[idx] = s;
}

// ------------- fused QKV v3: inline instance-norm of block input (R19; one
// stats-load + rsqrt per STAGING ROW, never per element — the R8 bug fixed
// per R10's uniform-load lesson) + R16-verified MFMA pointwise + depthwise
// conv3/conv15 + gate + layout. OOB halo stays 0 (conv pads the NORMED x).
// LDS: Xh @0 | Wh @9728 | o_tile @11776 -> 21504. grid (1024, 3 z), 256 thr.
__global__ __launch_bounds__(256) void k_qkv(const float* __restrict__ Xin,
    const float* __restrict__ stin, const float* __restrict__ ng,
    const float* __restrict__ nb, int hasn,
    const float* __restrict__ pwq, const float* __restrict__ pwk,
    const float* __restrict__ pwv,
    const float* __restrict__ d3q, const float* __restrict__ d15q, const float* __restrict__ gq,
    const float* __restrict__ d3k, const float* __restrict__ d15k, const float* __restrict__ gk,
    const float* __restrict__ d3v, const float* __restrict__ d15v, const float* __restrict__ gv,
    _Float16* __restrict__ Qt, _Float16* __restrict__ Kt, _Float16* __restrict__ Vt) {
  __shared__ __align__(16) char lds[21504];
  int z  = blockIdx.y;
  int bx = blockIdx.x;
  int bh = bx >> 4, lt = bx & 15, l0 = lt * 128;
  int b = bh >> 3, h = bh & 7;
  int t = threadIdx.x;
  const float* pwp  = (z == 0) ? pwq  : (z == 1) ? pwk  : pwv;
  const float* w3p  = (z == 0) ? d3q  : (z == 1) ? d3k  : d3v;
  const float* w15p = (z == 0) ? d15q : (z == 1) ? d15k : d15v;
  const float* gp   = (z == 0) ? gq   : (z == 1) ? gk   : gv;

  char* Xh = lds;                              // f16 [32 ci][152 m] rows 304B
  char* Wh = lds + 9728;                       // f16 [32 r][32 ci] rows 64B
  char* ot = lds + 11776;                      // pw out f16, 32 x 304B

  // ---- stage X -> f16 [ci][m] with inline norm (one rsqrt per row-thread)
  {
    int r = t >> 3, u = t & 7;
    const float* xr = Xin + ((size_t)b * CC + r) * LL;
    float scr = 1.f, shr = 0.f;
    if (hasn) norm_params(stin, ng, nb, b * 32 + r, r, scr, shr);
    char* xd = Xh + r * 304;
#pragma unroll
    for (int s = u; s < 36; s += 8) {
      int ls = l0 - 8 + s * 4;
      f4 v;
      if (ls >= 0 && ls + 3 < LL) {
        v = *(const f4*)(xr + ls);
#pragma unroll
        for (int e = 0; e < 4; ++e) v[e] = fmaf(v[e], scr, shr);
      } else {
#pragma unroll
        for (int e = 0; e < 4; ++e) {
          int l = ls + e;
          v[e] = (l >= 0 && l < LL) ? fmaf(xr[l], scr, shr) : 0.f;
        }
      }
      uint2 pk;
      pk.x = __builtin_bit_cast(unsigned, __builtin_amdgcn_cvt_pkrtz(v[0], v[1]));
      pk.y = __builtin_bit_cast(unsigned, __builtin_amdgcn_cvt_pkrtz(v[2], v[3]));
      *(uint2*)(xd + s * 8) = pk;
    }
  }
  // ---- stage W -> f16 [r][ci]
  {
    f4 wg = ((const f4*)(pwp + h * 1024))[t];
    uint2 pk;
    pk.x = __builtin_bit_cast(unsigned, __builtin_amdgcn_cvt_pkrtz(wg[0], wg[1]));
    pk.y = __builtin_bit_cast(unsigned, __builtin_amdgcn_cvt_pkrtz(wg[2], wg[3]));
    *(uint2*)(Wh + (t >> 3) * 64 + (t & 7) * 8) = pk;
  }
  __syncthreads();

  // ---- phase 1: pointwise conv as MFMA
  {
    int w4 = t >> 6, lane = t & 63;
    int g = lane >> 4, ln = lane & 15;
    h8 af[2];
#pragma unroll
    for (int mt = 0; mt < 2; ++mt)
      af[mt] = *(const h8*)(Wh + (mt * 16 + ln) * 64 + g * 16);
    for (int nt = w4; nt < 9; nt += 4) {
      h8 bf;
#pragma unroll
      for (int j = 0; j < 8; ++j)
        bf[j] = *(const _Float16*)(Xh + (g * 8 + j) * 304 + (nt * 16 + ln) * 2);
#pragma unroll
      for (int mt = 0; mt < 2; ++mt) {
        f4 zr = {0.f, 0.f, 0.f, 0.f};
        f4 d = __builtin_amdgcn_mfma_f32_16x16x32_f16(af[mt], bf, zr, 0, 0, 0);
#pragma unroll
        for (int i = 0; i < 4; ++i)
          *(_Float16*)(ot + (mt * 16 + g * 4 + i) * 304 + (nt * 16 + ln) * 2) =
              (_Float16)d[i];
      }
    }
  }
  __syncthreads();

  // ---- phase 2: depthwise conv3 + conv15 + softmax gate (unchanged)
  int c = t & 31, cg = t >> 5;
  float wv[32];
  {
    const h8* wp = (const h8*)(ot + c * 304 + cg * 32);
#pragma unroll
    for (int q4 = 0; q4 < 4; ++q4) {
      h8 v = wp[q4];
#pragma unroll
      for (int e = 0; e < 8; ++e) wv[q4 * 8 + e] = (float)v[e];
    }
  }
  float r0 = gp[0], r1 = gp[1];
  float mx = fmaxf(r0, r1);
  float e0 = __expf(r0 - mx), e1 = __expf(r1 - mx);
  float gi = 1.f / (e0 + e1);
  float g0 = e0 * gi, g1 = e1 * gi;
  float sc = (z == 0) ? 0.2550765737f : 1.0f;   // C^-0.5 * log2(e) fold
  int ch = h * 32 + c;
  float w3r[3], w15r[15];
#pragma unroll
  for (int k = 0; k < 3; ++k)  w3r[k]  = w3p[ch * 3 + k];
#pragma unroll
  for (int k = 0; k < 15; ++k) w15r[k] = w15p[ch * 15 + k];

  h8 olo, ohi;
#pragma unroll
  for (int i = 0; i < 16; ++i) {
    float a = 0.f;
#pragma unroll
    for (int k = 0; k < 3; ++k) a = fmaf(w3r[k], wv[i + 7 + k], a);
    float s15 = 0.f;
#pragma unroll
    for (int k = 0; k < 15; ++k) s15 = fmaf(w15r[k], wv[i + 1 + k], s15);
    float val = (g0 * a + g1 * s15) * sc;
    if (i < 8) olo[i] = (_Float16)val; else ohi[i - 8] = (_Float16)val;
  }

  if (z == 2) {
    _Float16* dst = Vt + ((size_t)bh * 32 + c) * LL + l0 + cg * 16;
    *(h8*)dst = olo;
    *(h8*)(dst + 8) = ohi;
  } else {
    char* tb = lds;                             // reuse Xh region (dead)
    __syncthreads();
#pragma unroll
    for (int i = 0; i < 16; ++i) {
      _Float16 v = (i < 8) ? olo[i] : ohi[i - 8];
      *(_Float16*)(tb + (cg * 16 + i) * 80 + c * 2) = v;
    }
    __syncthreads();
    _Float16* dst = ((z == 0) ? Qt : Kt) + ((size_t)bh * LL + l0) * 32;
    int l = t >> 1, hf = t & 1;
    uint4 a = *(uint4*)(tb + l * 80 + hf * 32);
    uint4 b2 = *(uint4*)(tb + l * 80 + hf * 32 + 16);
    *(uint4*)(dst + (size_t)l * 32 + hf * 16) = a;
    *(uint4*)(dst + (size_t)l * 32 + hf * 16 + 8) = b2;
  }
}

// ------------------------------------------------ MFMA flash attention (f16)
// R14-verified: XCD swizzle + R4/R6 core. Unchanged.
__global__ __launch_bounds__(512, 2) void k_attn(
    const _Float16* __restrict__ Qt, const _Float16* __restrict__ Kt,
    const _Float16* __restrict__ Vt, _Float16* __restrict__ AO) {
  __shared__ __align__(16) char lds[38912];
  const int tid  = threadIdx.x;
  const int lane = tid & 63;
  const int w    = tid >> 6;
  const int seg  = w >> 2;
  const int wq   = w & 3;
  const int g    = lane >> 4;
  const int ln   = lane & 15;
  const int h2c  = (wq >> 1) * 2;
  const int lin  = blockIdx.x + (blockIdx.y << 4);
  const int swz  = ((lin & 7) << 7) | (lin >> 3);
  const int qb   = swz & 15;
  const int bh   = swz >> 4;
  const _Float16* Qg = Qt + ((size_t)bh * LL + qb * 128) * 32;
  const _Float16* Kg = Kt + ((size_t)bh * LL + seg * 1024) * 32;
  const _Float16* Vg = Vt + (size_t)bh * 32 * LL + seg * 1024;

  h8 qf[2];
#pragma unroll
  for (int nt = 0; nt < 2; ++nt)
    qf[nt] = *(const h8*)(Qg + (size_t)(wq * 32 + nt * 16 + ln) * 32 + g * 8);

  h8 ones;
#pragma unroll
  for (int j = 0; j < 8; ++j) ones[j] = (_Float16)1.0f;

  char* kb = lds + seg * 5120;
  char* vb = lds + 20480 + seg * 4608;

  uint4 stg0, stg1;
  if ((wq & 1) == 0) {
    const uint4* gk = (const uint4*)Kg;
    stg0 = gk[h2c * 64 + lane];
    stg1 = gk[(h2c + 1) * 64 + lane];
    *(uint4*)(kb + (h2c * 16 + (lane >> 2)) * 80 + (lane & 3) * 16) = stg0;
    *(uint4*)(kb + ((h2c + 1) * 16 + (lane >> 2)) * 80 + (lane & 3) * 16) = stg1;
  } else {
    int c0 = h2c * 8 + (lane >> 3);
    stg0 = *(const uint4*)(Vg + (size_t)c0 * LL + (lane & 7) * 8);
    stg1 = *(const uint4*)(Vg + (size_t)(c0 + 8) * LL + (lane & 7) * 8);
    *(uint4*)(vb + c0 * 144 + (lane & 7) * 16) = stg0;
    *(uint4*)(vb + (c0 + 8) * 144 + (lane & 7) * 16) = stg1;
  }
  __syncthreads();

  f4 o[2][2];
#pragma unroll
  for (int ct = 0; ct < 2; ++ct)
#pragma unroll
    for (int nt = 0; nt < 2; ++nt) o[ct][nt] = (f4){0.f, 0.f, 0.f, 0.f};
  f4 sacc[2];
#pragma unroll
  for (int nt = 0; nt < 2; ++nt) sacc[nt] = (f4){0.f, 0.f, 0.f, 0.f};

  for (int it = 0; it < 16; ++it) {
    int pp = it & 1;
    char* kbc = kb + pp * 10240;
    char* vbc = vb + pp * 9216;
    if (it < 15) {
      int k0n = (it + 1) * 64;
      if ((wq & 1) == 0) {
        const uint4* gk = (const uint4*)(Kg + (size_t)k0n * 32);
        stg0 = gk[h2c * 64 + lane];
        stg1 = gk[(h2c + 1) * 64 + lane];
      } else {
        int c0 = h2c * 8 + (lane >> 3);
        stg0 = *(const uint4*)(Vg + (size_t)c0 * LL + k0n + (lane & 7) * 8);
        stg1 = *(const uint4*)(Vg + (size_t)(c0 + 8) * LL + k0n + (lane & 7) * 8);
      }
    }
#pragma unroll
    for (int chunk = 0; chunk < 2; ++chunk) {
      unsigned pa[2][2], pb[2][2];
#pragma unroll
      for (int mt2 = 0; mt2 < 2; ++mt2) {
        h8 kf = *(const h8*)(kbc + ((chunk * 2 + mt2) * 16 + ln) * 80 + g * 16);
#pragma unroll
        for (int nt = 0; nt < 2; ++nt) {
          f4 z = {0.f, 0.f, 0.f, 0.f};
          f4 s = __builtin_amdgcn_mfma_f32_16x16x32_f16(kf, qf[nt], z, 0, 0, 0);
          float p0 = __builtin_amdgcn_exp2f(s[0]);
          float p1 = __builtin_amdgcn_exp2f(s[1]);
          float p2 = __builtin_amdgcn_exp2f(s[2]);
          float p3 = __builtin_amdgcn_exp2f(s[3]);
          unsigned lo = __builtin_bit_cast(unsigned,
              __builtin_amdgcn_cvt_pkrtz(p0, p1));
          unsigned hi = __builtin_bit_cast(unsigned,
              __builtin_amdgcn_cvt_pkrtz(p2, p3));
          if (mt2 == 0) { pa[nt][0] = lo; pa[nt][1] = hi; }
          else          { pb[nt][0] = lo; pb[nt][1] = hi; }
        }
      }
      h8 vf[2];
#pragma unroll
      for (int ct = 0; ct < 2; ++ct)
        vf[ct] = *(const h8*)(vbc + (ct * 16 + ln) * 144 + chunk * 64 + g * 16);
#pragma unroll
      for (int nt = 0; nt < 2; ++nt) {
        unsigned w0 = pa[nt][0], w1 = pa[nt][1];
        unsigned w2 = pb[nt][0], w3 = pb[nt][1];
        asm("v_permlane32_swap_b32 %0, %1" : "+v"(w0), "+v"(w2));
        asm("v_permlane16_swap_b32 %0, %1" : "+v"(w0), "+v"(w2));
        asm("v_permlane32_swap_b32 %0, %1" : "+v"(w1), "+v"(w3));
        asm("v_permlane16_swap_b32 %0, %1" : "+v"(w1), "+v"(w3));
        uint4 pw4; pw4.x = w0; pw4.y = w1; pw4.z = w2; pw4.w = w3;
        h8 pf = __builtin_bit_cast(h8, pw4);
        sacc[nt] = __builtin_amdgcn_mfma_f32_16x16x32_f16(ones, pf, sacc[nt], 0, 0, 0);
        o[0][nt] = __builtin_amdgcn_mfma_f32_16x16x32_f16(vf[0], pf, o[0][nt], 0, 0, 0);
        o[1][nt] = __builtin_amdgcn_mfma_f32_16x16x32_f16(vf[1], pf, o[1][nt], 0, 0, 0);
      }
    }
    if (it < 15) {
      char* kbn = kb + (pp ^ 1) * 10240;
      char* vbn = vb + (pp ^ 1) * 9216;
      if ((wq & 1) == 0) {
        *(uint4*)(kbn + (h2c * 16 + (lane >> 2)) * 80 + (lane & 3) * 16) = stg0;
        *(uint4*)(kbn + ((h2c + 1) * 16 + (lane >> 2)) * 80 + (lane & 3) * 16) = stg1;
      } else {
        int c0 = h2c * 8 + (lane >> 3);
        *(uint4*)(vbn + c0 * 144 + (lane & 7) * 16) = stg0;
        *(uint4*)(vbn + (c0 + 8) * 144 + (lane & 7) * 16) = stg1;
      }
    }
    __syncthreads();
  }

  if (seg == 1) {
    char* eo = lds + wq * 9216 + lane * 144;
#pragma unroll
    for (int nt = 0; nt < 2; ++nt)
#pragma unroll
      for (int ct = 0; ct < 2; ++ct)
        *(f4*)(eo + (nt * 2 + ct) * 16) = o[ct][nt];
    f4 sv;
    sv[0] = sacc[0][0]; sv[1] = sacc[1][0];
    sv[2] = 0.f; sv[3] = 0.f;
    *(f4*)(eo + 64) = sv;
  }
  __syncthreads();
  if (seg == 0) {
    const char* po = lds + wq * 9216 + lane * 144;
    f4 s1v = *(const f4*)(po + 64);
    _Float16* out = AO + (size_t)bh * (32 * LL);
#pragma unroll
    for (int nt = 0; nt < 2; ++nt) {
      float inv = 1.f / (sacc[nt][0] + s1v[nt]);
      int qg = qb * 128 + wq * 32 + nt * 16 + ln;
#pragma unroll
      for (int ct = 0; ct < 2; ++ct) {
        f4 o1 = *(const f4*)(po + (nt * 2 + ct) * 16);
#pragma unroll
        for (int r = 0; r < 4; ++r)
          out[(size_t)(ct * 16 + g * 4 + r) * LL + qg] =
              (_Float16)((o[ct][nt][r] + o1[r]) * inv);
      }
    }
  }
}

// -------- uni GEMM v7: R17-verified MFMA + R19 norm fusion. Residual =
// inline norm of block input (params via 32 threads -> LDS, one rsqrt each);
// raw Y1 out + atomic per-(b,c) stats (16-wide shuffle reduce in the
// parallel D-fragment epilogue). LDS: Wh 32x560 | Bh 32x560 | nparams 256B.
__global__ __launch_bounds__(256) void k_uni_res(const _Float16* __restrict__ AO,
    const float* __restrict__ W, const float* __restrict__ bias,
    const float* __restrict__ Ain, const float* __restrict__ stin,
    const float* __restrict__ png, const float* __restrict__ pnb, int hasn,
    float* __restrict__ Y, float* __restrict__ stout) {
  __shared__ __align__(16) char lds[36096];
  char* Wh = lds;                               // f16 [c][cc], rows 560 B
  char* Bh = lds + 17920;                       // f16 [l][cc], rows 560 B
  float* nsc = (float*)(lds + 35840);           // [32]
  float* nsh = nsc + 32;                        // [32]
  int t  = threadIdx.x;
  int bx = blockIdx.x;                          // 512: b(8) x lt(64)
  int lt = bx & 63, b = bx >> 6;
  int l0 = lt * 32;

#pragma unroll
  for (int i = 0; i < 8; ++i) {
    int idx = t + i * 256;
    f4 wv4 = ((const f4*)W)[idx];
    uint2 pk;
    pk.x = __builtin_bit_cast(unsigned, __builtin_amdgcn_cvt_pkrtz(wv4[0], wv4[1]));
    pk.y = __builtin_bit_cast(unsigned, __builtin_amdgcn_cvt_pkrtz(wv4[2], wv4[3]));
    int c = idx >> 6, ccp = idx & 63;
    *(uint2*)(Wh + c * 560 + ccp * 8) = pk;
  }
#pragma unroll
  for (int it = 0; it < 4; ++it) {
    int cc = it * 64 + (t >> 2), chunk = t & 3;
    h8 av = *(const h8*)(AO + ((size_t)b * CHH + cc) * LL + l0 + chunk * 8);
#pragma unroll
    for (int e = 0; e < 8; ++e)
      *(_Float16*)(Bh + (chunk * 8 + e) * 560 + cc * 2) = av[e];
  }
  if (t < 32) {                                 // norm params once per block
    float scr = 1.f, shr = 0.f;
    if (hasn) norm_params(stin, png, pnb, b * 32 + t, t, scr, shr);
    nsc[t] = scr; nsh[t] = shr;
  }
  __syncthreads();

  int wv = t >> 6, lane = t & 63;
  int g = lane >> 4, ln = lane & 15;
  int mt = wv >> 1, nt2 = wv & 1;
  f4 acc = {0.f, 0.f, 0.f, 0.f};
#pragma unroll
  for (int ks = 0; ks < 8; ++ks) {
    h8 af = *(const h8*)(Wh + (mt * 16 + ln) * 560 + (ks * 32 + g * 8) * 2);
    h8 bf = *(const h8*)(Bh + (nt2 * 16 + ln) * 560 + (ks * 32 + g * 8) * 2);
    acc = __builtin_amdgcn_mfma_f32_16x16x32_f16(af, bf, acc, 0, 0, 0);
  }
#pragma unroll
  for (int i = 0; i < 4; ++i) {
    int c = mt * 16 + g * 4 + i;
    size_t o = ((size_t)b * CC + c) * LL + l0 + nt2 * 16 + ln;
    float res = fmaf(Ain[o], nsc[c], nsh[c]);
    float val = acc[i] + bias[c] + res;
    Y[o] = val;
    float a = val, v2 = val * val;              // reduce over ln (16 lanes)
#pragma unroll
    for (int off = 8; off; off >>= 1) {
      a  += __shfl_down(a, off, 16);
      v2 += __shfl_down(v2, off, 16);
    }
    if (ln == 0) {
      atomicAdd(&stout[(b * 32 + c) * 2], a);
      atomicAdd(&stout[(b * 32 + c) * 2 + 1], v2);
    }
  }
}

// -------- fused FFN v7: R18-verified dual-MFMA + R19 norm fusion. Inline
// norm1 of Y1 at staging (params per staging-row thread; t&7==0 publishes
// to LDS for the epilogue residual); raw Y2 out + atomic stats for norm2.
__global__ __launch_bounds__(256) void k_ffn(const float* __restrict__ Y1,
    const float* __restrict__ st1, const float* __restrict__ n1g,
    const float* __restrict__ n1b,
    const float* __restrict__ W1, const float* __restrict__ b1,
    const float* __restrict__ W2, const float* __restrict__ b2,
    float* __restrict__ Y2, float* __restrict__ stout) {
  __shared__ __align__(16) char lds[31232];
  char* Xh  = lds;                              // f16 [l][c]  rows 80 B
  char* W1h = lds + 2560;                       // f16 [o][c]  rows 80 B
  char* W2h = lds + 12800;                      // f16 [c][o]  rows 272 B
  char* Hh  = lds + 21504;                      // f16 [l][o]  rows 272 B
  float* b1h = (float*)(lds + 30208);           // 128 f32
  float* nsc = (float*)(lds + 30720);           // [32]
  float* nsh = nsc + 32;                        // [32]
  int t  = threadIdx.x;
  int bx = blockIdx.x;                          // 8b x 64lt
  int lt = bx & 63, b = bx >> 6;
  int l0 = lt * 32;

  // ---- stage norm1(Y1)^T -> f16 [l][c]; params once per row-thread
  {
    int c = t >> 3, le0 = (t & 7) * 4;
    float scr, shr;
    norm_params(st1, n1g, n1b, b * 32 + c, c, scr, shr);
    if ((t & 7) == 0) { nsc[c] = scr; nsh[c] = shr; }
    f4 v = *(const f4*)(Y1 + ((size_t)b * CC + c) * LL + l0 + le0);
#pragma unroll
    for (int e = 0; e < 4; ++e)
      *(_Float16*)(Xh + (le0 + e) * 80 + c * 2) = (_Float16)fmaf(v[e], scr, shr);
  }
#pragma unroll
  for (int i = 0; i < 4; ++i) {
    int idx = t + i * 256;
    f4 wv4 = ((const f4*)W1)[idx];
    uint2 pk;
    pk.x = __builtin_bit_cast(unsigned, __builtin_amdgcn_cvt_pkrtz(wv4[0], wv4[1]));
    pk.y = __builtin_bit_cast(unsigned, __builtin_amdgcn_cvt_pkrtz(wv4[2], wv4[3]));
    int o = idx >> 3, cp = idx & 7;
    *(uint2*)(W1h + o * 80 + cp * 8) = pk;
  }
#pragma unroll
  for (int i = 0; i < 4; ++i) {
    int idx = t + i * 256;
    f4 wv4 = ((const f4*)W2)[idx];
    uint2 pk;
    pk.x = __builtin_bit_cast(unsigned, __builtin_amdgcn_cvt_pkrtz(wv4[0], wv4[1]));
    pk.y = __builtin_bit_cast(unsigned, __builtin_amdgcn_cvt_pkrtz(wv4[2], wv4[3]));
    int c = idx >> 5, op = idx & 31;
    *(uint2*)(W2h + c * 272 + op * 8) = pk;
  }
  if (t < 128) b1h[t] = b1[t];
  __syncthreads();

  int w4 = t >> 6, lane = t & 63;
  int g = lane >> 4, ln = lane & 15;

  // ---- phase A: 16 tiles (8 ot x 2 lt2)
#pragma unroll
  for (int j = 0; j < 4; ++j) {
    int ti = w4 * 4 + j;
    int ot = ti >> 1, lt2 = ti & 1;
    h8 af = *(const h8*)(W1h + (ot * 16 + ln) * 80 + g * 16);
    h8 bf = *(const h8*)(Xh + (lt2 * 16 + ln) * 80 + g * 16);
    f4 zr = {0.f, 0.f, 0.f, 0.f};
    f4 d = __builtin_amdgcn_mfma_f32_16x16x32_f16(af, bf, zr, 0, 0, 0);
#pragma unroll
    for (int i = 0; i < 4; ++i) {
      int o = ot * 16 + g * 4 + i;
      float hv = fmaxf(d[i] + b1h[o], 0.f);
      *(_Float16*)(Hh + (lt2 * 16 + ln) * 272 + o * 2) = (_Float16)hv;
    }
  }
  __syncthreads();

  // ---- phase B: 4 tiles (2 ct2 x 2 lt2b), 4 k-steps
  int ct2 = w4 >> 1, lt2b = w4 & 1;
  f4 acc = {0.f, 0.f, 0.f, 0.f};
#pragma unroll
  for (int ks = 0; ks < 4; ++ks) {
    h8 af = *(const h8*)(W2h + (ct2 * 16 + ln) * 272 + (ks * 32 + g * 8) * 2);
    h8 bf = *(const h8*)(Hh + (lt2b * 16 + ln) * 272 + (ks * 32 + g * 8) * 2);
    acc = __builtin_amdgcn_mfma_f32_16x16x32_f16(af, bf, acc, 0, 0, 0);
  }
#pragma unroll
  for (int i = 0; i < 4; ++i) {
    int c = ct2 * 16 + g * 4 + i;
    size_t o = ((size_t)b * CC + c) * LL + l0 + lt2b * 16 + ln;
    float xn = fmaf(Y1[o], nsc[c], nsh[c]);     // f32 residual = norm1(Y1)
    float val = acc[i] + b2[c] + xn;
    Y2[o] = val;
    float a = val, v2 = val * val;
#pragma unroll
    for (int off = 8; off; off >>= 1) {
      a  += __shfl_down(a, off, 16);
      v2 += __shfl_down(v2, off, 16);
    }
    if (ln == 0) {
      atomicAdd(&stout[(b * 32 + c) * 2], a);
      atomicAdd(&stout[(b * 32 + c) * 2 + 1], v2);
    }
  }
}

// ------------------------------------------------------------- classifier
// inline norm2 of final layer output; params via LDS (32 threads, 1 rsqrt).
__global__ __launch_bounds__(256) void k_cls(const float* __restrict__ Y2,
    const float* __restrict__ st2, const float* __restrict__ n2g,
    const float* __restrict__ n2b,
    const float* __restrict__ W, const float* __restrict__ bias,
    float* __restrict__ out) {
  __shared__ float nsc[32], nsh[32];
  int idx = blockIdx.x * 256 + threadIdx.x;
  int l = idx & (LL - 1);
  int b = idx >> 11;
  if (threadIdx.x < 32) {
    float scr, shr;
    norm_params(st2, n2g, n2b, b * 32 + threadIdx.x, threadIdx.x, scr, shr);
    nsc[threadIdx.x] = scr; nsh[threadIdx.x] = shr;
  }
  __syncthreads();
  float s = bias[0];
#pragma unroll
  for (int c = 0; c < CC; ++c) {
    float xn = fmaf(Y2[((size_t)b * CC + c) * LL + l], nsc[c], nsh[c]);
    s = fmaf(W[c], xn, s);
  }
  out[idx] = 1.f / (1.f + __expf(-s));
}

// ------------------------------------------------------------------ launch
extern "C" void kernel_launch(void* const* d_in, const int* in_sizes, int n_in,
                              void* d_out, int out_size, void* d_ws,
                              size_t ws_size, hipStream_t stream) {
  const float* x      = (const float*)d_in[0];
  const float* enc_W  = (const float*)d_in[1];
  const float* enc_b  = (const float*)d_in[2];
  const float* pw_q   = (const float*)d_in[3];
  const float* dw3_q  = (const float*)d_in[4];
  const float* dw15_q = (const float*)d_in[5];
  const float* gate_q = (const float*)d_in[6];
  const float* pw_k   = (const float*)d_in[7];
  const float* dw3_k  = (const float*)d_in[8];
  const float* dw15_k = (const float*)d_in[9];
  const float* gate_k = (const float*)d_in[10];
  const float* pw_v   = (const float*)d_in[11];
  const float* dw3_v  = (const float*)d_in[12];
  const float* dw15_v = (const float*)d_in[13];
  const float* gate_v = (const float*)d_in[14];
  const float* uni_W  = (const float*)d_in[15];
  const float* uni_b  = (const float*)d_in[16];
  const float* n1_g   = (const float*)d_in[17];
  const float* n1_b   = (const float*)d_in[18];
  const float* n2_g   = (const float*)d_in[19];
  const float* n2_b   = (const float*)d_in[20];
  const float* ffn_W1 = (const float*)d_in[21];
  const float* ffn_b1 = (const float*)d_in[22];
  const float* ffn_W2 = (const float*)d_in[23];
  const float* ffn_b2 = (const float*)d_in[24];
  const float* cls_W  = (const float*)d_in[25];
  const float* cls_b  = (const float*)d_in[26];

  float* ws = (float*)d_ws;
  float* X0  = ws;                             // [B,32,L] fp32 enc out
  float* Y1  = ws + 524288;                    // [B,32,L] fp32 pre-norm1
  _Float16* AO = (_Float16*)(ws + 1048576);    // [B,256,L] f16 attn out
  float* Y2  = ws + 3145728;                   // [B,32,L] fp32 pre-norm2
  _Float16* Qt = (_Float16*)(ws + 9437184);    // [64bh][L][32c] f16
  _Float16* Kt = (_Float16*)(ws + 11534336);   // [64bh][L][32c] f16
  _Float16* Vt = (_Float16*)(ws + 13631488);   // [64bh][32c][L] f16
  float* st1 = ws + 15728640;                  // [6][8][32][2] f32
  float* st2 = st1 + 3072;                     // [6][8][32][2] f32

  hipMemsetAsync(st1, 0, 6144 * sizeof(float), stream);

  k_enc<<<2048, 256, 0, stream>>>(x, enc_W, enc_b, X0);

  for (int d = 0; d < DD; ++d) {
    const float* Ain = (d == 0) ? X0 : Y2;
    const float* stA = (d == 0) ? nullptr : st2 + (d - 1) * 512;
    const float* g2  = (d == 0) ? n2_g : n2_g + (d - 1) * CC;
    const float* b2p = (d == 0) ? n2_b : n2_b + (d - 1) * CC;
    int hasn = (d != 0);
    k_qkv<<<dim3(1024, 3), 256, 0, stream>>>(Ain, stA, g2, b2p, hasn,
        pw_q + d * CHH * CC, pw_k + d * CHH * CC, pw_v + d * CHH * CC,
        dw3_q + d * CHH * 3, dw15_q + d * CHH * 15, gate_q + d * 2,
        dw3_k + d * CHH * 3, dw15_k + d * CHH * 15, gate_k + d * 2,
        dw3_v + d * CHH * 3, dw15_v + d * CHH * 15, gate_v + d * 2,
        Qt, Kt, Vt);
    k_attn<<<dim3(16, 64), 512, 0, stream>>>(Qt, Kt, Vt, AO);
    k_uni_res<<<512, 256, 0, stream>>>(AO, uni_W + d * CC * CHH,
        uni_b + d * CC, Ain, stA, g2, b2p, hasn, Y1, st1 + d * 512);
    k_ffn<<<512, 256, 0, stream>>>(Y1, st1 + d * 512, n1_g + d * CC,
        n1_b + d * CC, ffn_W1 + d * 128 * CC, ffn_b1 + d * 128,
        ffn_W2 + d * CC * 128, ffn_b2 + d * CC, Y2, st2 + d * 512);
  }

  k_cls<<<64, 256, 0, stream>>>(Y2, st2 + 5 * 512, n2_g + 5 * CC,
                                n2_b + 5 * CC, cls_W, cls_b, (float*)d_out);
}

// Round 20
// 611.299 us; speedup vs baseline: 1.4281x; 1.4281x over previous
//
#include <hip/hip_runtime.h>
#include <math.h>

#define LL   2048
#define BB   8
#define CC   32
#define CHH  256
#define HH   8
#define DD   6

typedef _Float16 h8 __attribute__((ext_vector_type(8)));
typedef _Float16 h4 __attribute__((ext_vector_type(4)));
typedef float f4 __attribute__((ext_vector_type(4)));
typedef float f2v __attribute__((ext_vector_type(2)));

// ---------------------------------------------------------------- encoder
__global__ __launch_bounds__(256) void k_enc(const float* __restrict__ x,
    const float* __restrict__ W, const float* __restrict__ bias,
    float* __restrict__ X) {
  int idx = blockIdx.x * 256 + threadIdx.x;          // B*32*L = 524288
  int l = idx & (LL - 1);
  int c = (idx >> 11) & 31;
  int b = idx >> 16;
  float s = bias[c];
#pragma unroll
  for (int i = 0; i < 6; ++i)
    s = fmaf(W[c * 6 + i], x[((size_t)b * 6 + i) * LL + l], s);
  X[idx] = s;
}

// ------------- fused QKV v2 (R16-verified): MFMA pointwise conv + depthwise
// conv3/conv15 + gate + cvt + layout. 18 mfma 16x16x32 tiles; ~45 LDS
// ops/lane (was 320). LDS: Xh @0 | Wh @9728 | o_tile @11776 -> 21504.
// grid (1024 = bh*16+lt, 3 z), 256 thr.
__global__ __launch_bounds__(256) void k_qkv(const float* __restrict__ X,
    const float* __restrict__ pwq, const float* __restrict__ pwk,
    const float* __restrict__ pwv,
    const float* __restrict__ d3q, const float* __restrict__ d15q, const float* __restrict__ gq,
    const float* __restrict__ d3k, const float* __restrict__ d15k, const float* __restrict__ gk,
    const float* __restrict__ d3v, const float* __restrict__ d15v, const float* __restrict__ gv,
    _Float16* __restrict__ Qt, _Float16* __restrict__ Kt, _Float16* __restrict__ Vt) {
  __shared__ __align__(16) char lds[21504];
  int z  = blockIdx.y;
  int bx = blockIdx.x;
  int bh = bx >> 4, lt = bx & 15, l0 = lt * 128;
  int b = bh >> 3, h = bh & 7;
  int t = threadIdx.x;
  const float* pwp  = (z == 0) ? pwq  : (z == 1) ? pwk  : pwv;
  const float* w3p  = (z == 0) ? d3q  : (z == 1) ? d3k  : d3v;
  const float* w15p = (z == 0) ? d15q : (z == 1) ? d15k : d15v;
  const float* gp   = (z == 0) ? gq   : (z == 1) ? gk   : gv;

  char* Xh = lds;                              // f16 [32 ci][152 m] rows 304B
  char* Wh = lds + 9728;                       // f16 [32 r][32 ci] rows 64B
  char* ot = lds + 11776;                      // pw out f16, 32 x 304B

  // ---- stage X -> f16 [ci][m], m = l-(l0-8) in [0,144), OOB zero
  {
    int r = t >> 3, u = t & 7;
    const float* xr = X + ((size_t)b * CC + r) * LL;
    char* xd = Xh + r * 304;
#pragma unroll
    for (int s = u; s < 36; s += 8) {
      int ls = l0 - 8 + s * 4;
      f4 v;
      if (ls >= 0 && ls + 3 < LL) {
        v = *(const f4*)(xr + ls);
      } else {
#pragma unroll
        for (int e = 0; e < 4; ++e) {
          int l = ls + e;
          v[e] = (l >= 0 && l < LL) ? xr[l] : 0.f;
        }
      }
      uint2 pk;
      pk.x = __builtin_bit_cast(unsigned, __builtin_amdgcn_cvt_pkrtz(v[0], v[1]));
      pk.y = __builtin_bit_cast(unsigned, __builtin_amdgcn_cvt_pkrtz(v[2], v[3]));
      *(uint2*)(xd + s * 8) = pk;
    }
  }
  // ---- stage W -> f16 [r][ci]
  {
    f4 wg = ((const f4*)(pwp + h * 1024))[t];  // och = t>>3, ci0 = (t&7)*4
    uint2 pk;
    pk.x = __builtin_bit_cast(unsigned, __builtin_amdgcn_cvt_pkrtz(wg[0], wg[1]));
    pk.y = __builtin_bit_cast(unsigned, __builtin_amdgcn_cvt_pkrtz(wg[2], wg[3]));
    *(uint2*)(Wh + (t >> 3) * 64 + (t & 7) * 8) = pk;
  }
  __syncthreads();

  // ---- phase 1: pointwise conv as MFMA.  out[r][m] = sum_ci W[r][ci]X[ci][m]
  {
    int w4 = t >> 6, lane = t & 63;
    int g = lane >> 4, ln = lane & 15;
    h8 af[2];
#pragma unroll
    for (int mt = 0; mt < 2; ++mt)
      af[mt] = *(const h8*)(Wh + (mt * 16 + ln) * 64 + g * 16);
    for (int nt = w4; nt < 9; nt += 4) {
      h8 bf;
#pragma unroll
      for (int j = 0; j < 8; ++j)
        bf[j] = *(const _Float16*)(Xh + (g * 8 + j) * 304 + (nt * 16 + ln) * 2);
#pragma unroll
      for (int mt = 0; mt < 2; ++mt) {
        f4 zr = {0.f, 0.f, 0.f, 0.f};
        f4 d = __builtin_amdgcn_mfma_f32_16x16x32_f16(af[mt], bf, zr, 0, 0, 0);
#pragma unroll
        for (int i = 0; i < 4; ++i)
          *(_Float16*)(ot + (mt * 16 + g * 4 + i) * 304 + (nt * 16 + ln) * 2) =
              (_Float16)d[i];
      }
    }
  }
  __syncthreads();

  // ---- phase 2: depthwise conv3 + conv15 + softmax gate (unchanged)
  int c = t & 31, cg = t >> 5;
  float wv[32];
  {
    const h8* wp = (const h8*)(ot + c * 304 + cg * 32);
#pragma unroll
    for (int q4 = 0; q4 < 4; ++q4) {
      h8 v = wp[q4];
#pragma unroll
      for (int e = 0; e < 8; ++e) wv[q4 * 8 + e] = (float)v[e];
    }
  }
  float r0 = gp[0], r1 = gp[1];
  float mx = fmaxf(r0, r1);
  float e0 = __expf(r0 - mx), e1 = __expf(r1 - mx);
  float gi = 1.f / (e0 + e1);
  float g0 = e0 * gi, g1 = e1 * gi;
  float sc = (z == 0) ? 0.2550765737f : 1.0f;   // C^-0.5 * log2(e) fold
  int ch = h * 32 + c;
  float w3r[3], w15r[15];
#pragma unroll
  for (int k = 0; k < 3; ++k)  w3r[k]  = w3p[ch * 3 + k];
#pragma unroll
  for (int k = 0; k < 15; ++k) w15r[k] = w15p[ch * 15 + k];

  h8 olo, ohi;
#pragma unroll
  for (int i = 0; i < 16; ++i) {
    float a = 0.f;
#pragma unroll
    for (int k = 0; k < 3; ++k) a = fmaf(w3r[k], wv[i + 7 + k], a);
    float s15 = 0.f;
#pragma unroll
    for (int k = 0; k < 15; ++k) s15 = fmaf(w15r[k], wv[i + 1 + k], s15);
    float val = (g0 * a + g1 * s15) * sc;
    if (i < 8) olo[i] = (_Float16)val; else ohi[i - 8] = (_Float16)val;
  }

  if (z == 2) {
    _Float16* dst = Vt + ((size_t)bh * 32 + c) * LL + l0 + cg * 16;
    *(h8*)dst = olo;
    *(h8*)(dst + 8) = ohi;
  } else {
    char* tb = lds;                             // reuse Xh region (dead)
    __syncthreads();
#pragma unroll
    for (int i = 0; i < 16; ++i) {
      _Float16 v = (i < 8) ? olo[i] : ohi[i - 8];
      *(_Float16*)(tb + (cg * 16 + i) * 80 + c * 2) = v;
    }
    __syncthreads();
    _Float16* dst = ((z == 0) ? Qt : Kt) + ((size_t)bh * LL + l0) * 32;
    int l = t >> 1, hf = t & 1;
    uint4 a = *(uint4*)(tb + l * 80 + hf * 32);
    uint4 b2 = *(uint4*)(tb + l * 80 + hf * 32 + 16);
    *(uint4*)(dst + (size_t)l * 32 + hf * 16) = a;
    *(uint4*)(dst + (size_t)l * 32 + hf * 16 + 8) = b2;
  }
}

// ------------------------------------------------ MFMA flash attention (f16)
// R14-verified: XCD-aware block swizzle (FETCH 69.7->12.3 MB confirmed) +
// R4/R6 core: 8 waves, key-split, dbuf LDS, native exp2, permlane PV
// fragment, in-LDS merge.
__global__ __launch_bounds__(512, 2) void k_attn(
    const _Float16* __restrict__ Qt, const _Float16* __restrict__ Kt,
    const _Float16* __restrict__ Vt, _Float16* __restrict__ AO) {
  __shared__ __align__(16) char lds[38912];
  const int tid  = threadIdx.x;
  const int lane = tid & 63;
  const int w    = tid >> 6;                   // 0..7
  const int seg  = w >> 2;                     // 0..1: key segment
  const int wq   = w & 3;                      // q sub-block within 128
  const int g    = lane >> 4;
  const int ln   = lane & 15;
  const int h2c  = (wq >> 1) * 2;
  const int lin  = blockIdx.x + (blockIdx.y << 4);        // 0..1023
  const int swz  = ((lin & 7) << 7) | (lin >> 3);         // XCD-grouped
  const int qb   = swz & 15;                   // 0..15
  const int bh   = swz >> 4;                   // 0..63
  const _Float16* Qg = Qt + ((size_t)bh * LL + qb * 128) * 32;
  const _Float16* Kg = Kt + ((size_t)bh * LL + seg * 1024) * 32;
  const _Float16* Vg = Vt + (size_t)bh * 32 * LL + seg * 1024;

  h8 qf[2];
#pragma unroll
  for (int nt = 0; nt < 2; ++nt)
    qf[nt] = *(const h8*)(Qg + (size_t)(wq * 32 + nt * 16 + ln) * 32 + g * 8);

  h8 ones;
#pragma unroll
  for (int j = 0; j < 8; ++j) ones[j] = (_Float16)1.0f;

  char* kb = lds + seg * 5120;                 // + p*10240
  char* vb = lds + 20480 + seg * 4608;         // + p*9216

  uint4 stg0, stg1;
  if ((wq & 1) == 0) {
    const uint4* gk = (const uint4*)Kg;
    stg0 = gk[h2c * 64 + lane];
    stg1 = gk[(h2c + 1) * 64 + lane];
    *(uint4*)(kb + (h2c * 16 + (lane >> 2)) * 80 + (lane & 3) * 16) = stg0;
    *(uint4*)(kb + ((h2c + 1) * 16 + (lane >> 2)) * 80 + (lane & 3) * 16) = stg1;
  } else {
    int c0 = h2c * 8 + (lane >> 3);
    stg0 = *(const uint4*)(Vg + (size_t)c0 * LL + (lane & 7) * 8);
    stg1 = *(const uint4*)(Vg + (size_t)(c0 + 8) * LL + (lane & 7) * 8);
    *(uint4*)(vb + c0 * 144 + (lane & 7) * 16) = stg0;
    *(uint4*)(vb + (c0 + 8) * 144 + (lane & 7) * 16) = stg1;
  }
  __syncthreads();

  f4 o[2][2];
#pragma unroll
  for (int ct = 0; ct < 2; ++ct)
#pragma unroll
    for (int nt = 0; nt < 2; ++nt) o[ct][nt] = (f4){0.f, 0.f, 0.f, 0.f};
  f4 sacc[2];
#pragma unroll
  for (int nt = 0; nt < 2; ++nt) sacc[nt] = (f4){0.f, 0.f, 0.f, 0.f};

  for (int it = 0; it < 16; ++it) {
    int pp = it & 1;
    char* kbc = kb + pp * 10240;
    char* vbc = vb + pp * 9216;
    if (it < 15) {
      int k0n = (it + 1) * 64;
      if ((wq & 1) == 0) {
        const uint4* gk = (const uint4*)(Kg + (size_t)k0n * 32);
        stg0 = gk[h2c * 64 + lane];
        stg1 = gk[(h2c + 1) * 64 + lane];
      } else {
        int c0 = h2c * 8 + (lane >> 3);
        stg0 = *(const uint4*)(Vg + (size_t)c0 * LL + k0n + (lane & 7) * 8);
        stg1 = *(const uint4*)(Vg + (size_t)(c0 + 8) * LL + k0n + (lane & 7) * 8);
      }
    }
#pragma unroll
    for (int chunk = 0; chunk < 2; ++chunk) {
      unsigned pa[2][2], pb[2][2];
#pragma unroll
      for (int mt2 = 0; mt2 < 2; ++mt2) {
        h8 kf = *(const h8*)(kbc + ((chunk * 2 + mt2) * 16 + ln) * 80 + g * 16);
#pragma unroll
        for (int nt = 0; nt < 2; ++nt) {
          f4 z = {0.f, 0.f, 0.f, 0.f};
          f4 s = __builtin_amdgcn_mfma_f32_16x16x32_f16(kf, qf[nt], z, 0, 0, 0);
          float p0 = __builtin_amdgcn_exp2f(s[0]);
          float p1 = __builtin_amdgcn_exp2f(s[1]);
          float p2 = __builtin_amdgcn_exp2f(s[2]);
          float p3 = __builtin_amdgcn_exp2f(s[3]);
          unsigned lo = __builtin_bit_cast(unsigned,
              __builtin_amdgcn_cvt_pkrtz(p0, p1));
          unsigned hi = __builtin_bit_cast(unsigned,
              __builtin_amdgcn_cvt_pkrtz(p2, p3));
          if (mt2 == 0) { pa[nt][0] = lo; pa[nt][1] = hi; }
          else          { pb[nt][0] = lo; pb[nt][1] = hi; }
        }
      }
      h8 vf[2];
#pragma unroll
      for (int ct = 0; ct < 2; ++ct)
        vf[ct] = *(const h8*)(vbc + (ct * 16 + ln) * 144 + chunk * 64 + g * 16);
#pragma unroll
      for (int nt = 0; nt < 2; ++nt) {
        unsigned w0 = pa[nt][0], w1 = pa[nt][1];
        unsigned w2 = pb[nt][0], w3 = pb[nt][1];
        asm("v_permlane32_swap_b32 %0, %1" : "+v"(w0), "+v"(w2));
        asm("v_permlane16_swap_b32 %0, %1" : "+v"(w0), "+v"(w2));
        asm("v_permlane32_swap_b32 %0, %1" : "+v"(w1), "+v"(w3));
        asm("v_permlane16_swap_b32 %0, %1" : "+v"(w1), "+v"(w3));
        uint4 pw4; pw4.x = w0; pw4.y = w1; pw4.z = w2; pw4.w = w3;
        h8 pf = __builtin_bit_cast(h8, pw4);
        sacc[nt] = __builtin_amdgcn_mfma_f32_16x16x32_f16(ones, pf, sacc[nt], 0, 0, 0);
        o[0][nt] = __builtin_amdgcn_mfma_f32_16x16x32_f16(vf[0], pf, o[0][nt], 0, 0, 0);
        o[1][nt] = __builtin_amdgcn_mfma_f32_16x16x32_f16(vf[1], pf, o[1][nt], 0, 0, 0);
      }
    }
    if (it < 15) {
      char* kbn = kb + (pp ^ 1) * 10240;
      char* vbn = vb + (pp ^ 1) * 9216;
      if ((wq & 1) == 0) {
        *(uint4*)(kbn + (h2c * 16 + (lane >> 2)) * 80 + (lane & 3) * 16) = stg0;
        *(uint4*)(kbn + ((h2c + 1) * 16 + (lane >> 2)) * 80 + (lane & 3) * 16) = stg1;
      } else {
        int c0 = h2c * 8 + (lane >> 3);
        *(uint4*)(vbn + c0 * 144 + (lane & 7) * 16) = stg0;
        *(uint4*)(vbn + (c0 + 8) * 144 + (lane & 7) * 16) = stg1;
      }
    }
    __syncthreads();
  }

  if (seg == 1) {
    char* eo = lds + wq * 9216 + lane * 144;
#pragma unroll
    for (int nt = 0; nt < 2; ++nt)
#pragma unroll
      for (int ct = 0; ct < 2; ++ct)
        *(f4*)(eo + (nt * 2 + ct) * 16) = o[ct][nt];
    f4 sv;
    sv[0] = sacc[0][0]; sv[1] = sacc[1][0];
    sv[2] = 0.f; sv[3] = 0.f;
    *(f4*)(eo + 64) = sv;
  }
  __syncthreads();
  if (seg == 0) {
    const char* po = lds + wq * 9216 + lane * 144;
    f4 s1v = *(const f4*)(po + 64);
    _Float16* out = AO + (size_t)bh * (32 * LL);
#pragma unroll
    for (int nt = 0; nt < 2; ++nt) {
      float inv = 1.f / (sacc[nt][0] + s1v[nt]);
      int qg = qb * 128 + wq * 32 + nt * 16 + ln;
#pragma unroll
      for (int ct = 0; ct < 2; ++ct) {
        f4 o1 = *(const f4*)(po + (nt * 2 + ct) * 16);
#pragma unroll
        for (int r = 0; r < 4; ++r)
          out[(size_t)(ct * 16 + g * 4 + r) * LL + qg] =
              (_Float16)((o[ct][nt][r] + o1[r]) * inv);
      }
    }
  }
}

// -------- uni GEMM v6 (R17-verified): MFMA. A = W f16, B = AO^T via LDS
// transpose, 8 k-steps mfma 16x16x32, D-fragment epilogue with bias+residual.
// LDS: Wh 32x560 @0 | Bh 32x560 @17920 -> 35840. grid 512, 4 waves.
__global__ __launch_bounds__(256) void k_uni_res(const _Float16* __restrict__ AO,
    const float* __restrict__ W, const float* __restrict__ bias,
    const float* __restrict__ Xin, float* __restrict__ Y) {
  __shared__ __align__(16) char lds[35840];
  char* Wh = lds;                               // f16 [c][cc], rows 560 B
  char* Bh = lds + 17920;                       // f16 [l][cc], rows 560 B
  int t  = threadIdx.x;
  int bx = blockIdx.x;                          // 512: b(8) x lt(64)
  int lt = bx & 63, b = bx >> 6;
  int l0 = lt * 32;

#pragma unroll
  for (int i = 0; i < 8; ++i) {
    int idx = t + i * 256;                      // f4 index; 2048 total
    f4 wv4 = ((const f4*)W)[idx];
    uint2 pk;
    pk.x = __builtin_bit_cast(unsigned, __builtin_amdgcn_cvt_pkrtz(wv4[0], wv4[1]));
    pk.y = __builtin_bit_cast(unsigned, __builtin_amdgcn_cvt_pkrtz(wv4[2], wv4[3]));
    int c = idx >> 6, ccp = idx & 63;
    *(uint2*)(Wh + c * 560 + ccp * 8) = pk;
  }
#pragma unroll
  for (int it = 0; it < 4; ++it) {
    int cc = it * 64 + (t >> 2), chunk = t & 3;
    h8 av = *(const h8*)(AO + ((size_t)b * CHH + cc) * LL + l0 + chunk * 8);
#pragma unroll
    for (int e = 0; e < 8; ++e)
      *(_Float16*)(Bh + (chunk * 8 + e) * 560 + cc * 2) = av[e];
  }
  __syncthreads();

  int wv = t >> 6, lane = t & 63;
  int g = lane >> 4, ln = lane & 15;
  int mt = wv >> 1, nt2 = wv & 1;
  f4 acc = {0.f, 0.f, 0.f, 0.f};
#pragma unroll
  for (int ks = 0; ks < 8; ++ks) {
    h8 af = *(const h8*)(Wh + (mt * 16 + ln) * 560 + (ks * 32 + g * 8) * 2);
    h8 bf = *(const h8*)(Bh + (nt2 * 16 + ln) * 560 + (ks * 32 + g * 8) * 2);
    acc = __builtin_amdgcn_mfma_f32_16x16x32_f16(af, bf, acc, 0, 0, 0);
  }
#pragma unroll
  for (int i = 0; i < 4; ++i) {
    int c = mt * 16 + g * 4 + i;
    size_t o = ((size_t)b * CC + c) * LL + l0 + nt2 * 16 + ln;
    Y[o] = acc[i] + bias[c] + Xin[o];
  }
}

// ---------------------------------------------------------- instance norm
// (R10-verified form: 512 threads, 4 elems/thread.)
__global__ __launch_bounds__(512) void k_inorm(const float* __restrict__ Y,
    float* __restrict__ X, const float* __restrict__ g,
    const float* __restrict__ bt) {
  __shared__ float red[16];
  int row = blockIdx.x;
  int c = row & 31;
  const float* y = Y + (size_t)row * LL;
  float v[4];
  float s = 0.f, ss = 0.f;
#pragma unroll
  for (int i = 0; i < 4; ++i) {
    v[i] = y[threadIdx.x + 512 * i];
    s += v[i];
    ss = fmaf(v[i], v[i], ss);
  }
#pragma unroll
  for (int off = 32; off; off >>= 1) {
    s  += __shfl_down(s, off);
    ss += __shfl_down(ss, off);
  }
  int wid = threadIdx.x >> 6;
  if ((threadIdx.x & 63) == 0) { red[wid * 2] = s; red[wid * 2 + 1] = ss; }
  __syncthreads();
  if (threadIdx.x == 0) {
    float rs0 = 0.f, rs1 = 0.f;
#pragma unroll
    for (int i = 0; i < 8; ++i) { rs0 += red[i * 2]; rs1 += red[i * 2 + 1]; }
    red[0] = rs0; red[1] = rs1;
  }
  __syncthreads();
  float mean = red[0] * (1.f / LL);
  float var  = red[1] * (1.f / LL) - mean * mean;
  float rs = rsqrtf(var + 1e-5f) * g[c];
  float bb = bt[c];
#pragma unroll
  for (int i = 0; i < 4; ++i)
    X[(size_t)row * LL + threadIdx.x + 512 * i] = (v[i] - mean) * rs + bb;
}

// -------- fused FFN v6 (R18-verified): both GEMMs on MFMA.
// Phase A: h[128o][32l] = W1 x X^T (16 tiles, k=32 one step), +b1, relu on
// f32 D-fragment, fragment-scatter into Hh[l][o] (free transpose).
// Phase B: out[32c][32l] = W2 x h (4 tiles x 4 k-steps), +b2 + residual.
// LDS: Xh 32x80 @0 | W1h 128x80 @2560 | W2h 32x272 @12800 | Hh 32x272
// @21504 | b1h 128f @30208 -> 30720. grid 512 (8b x 64lt) = 2 blocks/CU.
__global__ __launch_bounds__(256) void k_ffn(const float* __restrict__ X,
    const float* __restrict__ W1, const float* __restrict__ b1,
    const float* __restrict__ W2, const float* __restrict__ b2,
    float* __restrict__ Y) {
  __shared__ __align__(16) char lds[30720];
  char* Xh  = lds;                              // f16 [l][c]  rows 80 B
  char* W1h = lds + 2560;                       // f16 [o][c]  rows 80 B
  char* W2h = lds + 12800;                      // f16 [c][o]  rows 272 B
  char* Hh  = lds + 21504;                      // f16 [l][o]  rows 272 B
  float* b1h = (float*)(lds + 30208);           // 128 f32
  int t  = threadIdx.x;
  int bx = blockIdx.x;                          // 8b x 64lt
  int lt = bx & 63, b = bx >> 6;
  int l0 = lt * 32;

  // ---- stage X^T -> f16 [l][c]: c = t>>3, le0 = (t&7)*4
  {
    int c = t >> 3, le0 = (t & 7) * 4;
    f4 v = *(const f4*)(X + ((size_t)b * CC + c) * LL + l0 + le0);
#pragma unroll
    for (int e = 0; e < 4; ++e)
      *(_Float16*)(Xh + (le0 + e) * 80 + c * 2) = (_Float16)v[e];
  }
  // ---- stage W1 -> f16 [o][c] (4 f4/thread)
#pragma unroll
  for (int i = 0; i < 4; ++i) {
    int idx = t + i * 256;                      // 1024 f4 total
    f4 wv4 = ((const f4*)W1)[idx];
    uint2 pk;
    pk.x = __builtin_bit_cast(unsigned, __builtin_amdgcn_cvt_pkrtz(wv4[0], wv4[1]));
    pk.y = __builtin_bit_cast(unsigned, __builtin_amdgcn_cvt_pkrtz(wv4[2], wv4[3]));
    int o = idx >> 3, cp = idx & 7;             // 8 f4 per 32-c row
    *(uint2*)(W1h + o * 80 + cp * 8) = pk;
  }
  // ---- stage W2 -> f16 [c][o] (4 f4/thread)
#pragma unroll
  for (int i = 0; i < 4; ++i) {
    int idx = t + i * 256;                      // 1024 f4 total
    f4 wv4 = ((const f4*)W2)[idx];
    uint2 pk;
    pk.x = __builtin_bit_cast(unsigned, __builtin_amdgcn_cvt_pkrtz(wv4[0], wv4[1]));
    pk.y = __builtin_bit_cast(unsigned, __builtin_amdgcn_cvt_pkrtz(wv4[2], wv4[3]));
    int c = idx >> 5, op = idx & 31;            // 32 f4 per 128-o row
    *(uint2*)(W2h + c * 272 + op * 8) = pk;
  }
  if (t < 128) b1h[t] = b1[t];
  __syncthreads();

  int w4 = t >> 6, lane = t & 63;
  int g = lane >> 4, ln = lane & 15;

  // ---- phase A: 16 tiles (8 ot x 2 lt2); wave w4 does ti = w4*4+j
#pragma unroll
  for (int j = 0; j < 4; ++j) {
    int ti = w4 * 4 + j;
    int ot = ti >> 1, lt2 = ti & 1;
    h8 af = *(const h8*)(W1h + (ot * 16 + ln) * 80 + g * 16);
    h8 bf = *(const h8*)(Xh + (lt2 * 16 + ln) * 80 + g * 16);
    f4 zr = {0.f, 0.f, 0.f, 0.f};
    f4 d = __builtin_amdgcn_mfma_f32_16x16x32_f16(af, bf, zr, 0, 0, 0);
#pragma unroll
    for (int i = 0; i < 4; ++i) {
      int o = ot * 16 + g * 4 + i;
      float hv = fmaxf(d[i] + b1h[o], 0.f);
      *(_Float16*)(Hh + (lt2 * 16 + ln) * 272 + o * 2) = (_Float16)hv;
    }
  }
  __syncthreads();

  // ---- phase B: 4 tiles (2 ct2 x 2 lt2b), 4 k-steps each
  int ct2 = w4 >> 1, lt2b = w4 & 1;
  f4 acc = {0.f, 0.f, 0.f, 0.f};
#pragma unroll
  for (int ks = 0; ks < 4; ++ks) {
    h8 af = *(const h8*)(W2h + (ct2 * 16 + ln) * 272 + (ks * 32 + g * 8) * 2);
    h8 bf = *(const h8*)(Hh + (lt2b * 16 + ln) * 272 + (ks * 32 + g * 8) * 2);
    acc = __builtin_amdgcn_mfma_f32_16x16x32_f16(af, bf, acc, 0, 0, 0);
  }
#pragma unroll
  for (int i = 0; i < 4; ++i) {
    int c = ct2 * 16 + g * 4 + i;
    size_t o = ((size_t)b * CC + c) * LL + l0 + lt2b * 16 + ln;
    Y[o] = acc[i] + b2[c] + X[o];
  }
}

// ------------------------------------------------------------- classifier
__global__ __launch_bounds__(256) void k_cls(const float* __restrict__ X,
    const float* __restrict__ W, const float* __restrict__ bias,
    float* __restrict__ out) {
  int idx = blockIdx.x * 256 + threadIdx.x;
  int l = idx & (LL - 1);
  int b = idx >> 11;
  float s = bias[0];
#pragma unroll
  for (int c = 0; c < CC; ++c)
    s = fmaf(W[c], X[((size_t)b * CC + c) * LL + l], s);
  out[idx] = 1.f / (1.f + __expf(-s));
}

// ------------------------------------------------------------------ launch
extern "C" void kernel_launch(void* const* d_in, const int* in_sizes, int n_in,
                              void* d_out, int out_size, void* d_ws,
                              size_t ws_size, hipStream_t stream) {
  const float* x      = (const float*)d_in[0];
  const float* enc_W  = (const float*)d_in[1];
  const float* enc_b  = (const float*)d_in[2];
  const float* pw_q   = (const float*)d_in[3];
  const float* dw3_q  = (const float*)d_in[4];
  const float* dw15_q = (const float*)d_in[5];
  const float* gate_q = (const float*)d_in[6];
  const float* pw_k   = (const float*)d_in[7];
  const float* dw3_k  = (const float*)d_in[8];
  const float* dw15_k = (const float*)d_in[9];
  const float* gate_k = (const float*)d_in[10];
  const float* pw_v   = (const float*)d_in[11];
  const float* dw3_v  = (const float*)d_in[12];
  const float* dw15_v = (const float*)d_in[13];
  const float* gate_v = (const float*)d_in[14];
  const float* uni_W  = (const float*)d_in[15];
  const float* uni_b  = (const float*)d_in[16];
  const float* n1_g   = (const float*)d_in[17];
  const float* n1_b   = (const float*)d_in[18];
  const float* n2_g   = (const float*)d_in[19];
  const float* n2_b   = (const float*)d_in[20];
  const float* ffn_W1 = (const float*)d_in[21];
  const float* ffn_b1 = (const float*)d_in[22];
  const float* ffn_W2 = (const float*)d_in[23];
  const float* ffn_b2 = (const float*)d_in[24];
  const float* cls_W  = (const float*)d_in[25];
  const float* cls_b  = (const float*)d_in[26];

  float* ws = (float*)d_ws;
  float* X   = ws;                             // [B,32,L] fp32
  float* Y   = ws + 524288;                    // [B,32,L] fp32
  _Float16* AO = (_Float16*)(ws + 1048576);    // [B,256,L] f16 attn out
  _Float16* Qt = (_Float16*)(ws + 9437184);    // [64bh][L][32c] f16
  _Float16* Kt = (_Float16*)(ws + 11534336);   // [64bh][L][32c] f16
  _Float16* Vt = (_Float16*)(ws + 13631488);   // [64bh][32c][L] f16

  k_enc<<<2048, 256, 0, stream>>>(x, enc_W, enc_b, X);

  for (int d = 0; d < DD; ++d) {
    k_qkv<<<dim3(1024, 3), 256, 0, stream>>>(X,
        pw_q + d * CHH * CC, pw_k + d * CHH * CC, pw_v + d * CHH * CC,
        dw3_q + d * CHH * 3, dw15_q + d * CHH * 15, gate_q + d * 2,
        dw3_k + d * CHH * 3, dw15_k + d * CHH * 15, gate_k + d * 2,
        dw3_v + d * CHH * 3, dw15_v + d * CHH * 15, gate_v + d * 2,
        Qt, Kt, Vt);
    k_attn<<<dim3(16, 64), 512, 0, stream>>>(Qt, Kt, Vt, AO);
    k_uni_res<<<512, 256, 0, stream>>>(AO, uni_W + d * CC * CHH,
                                       uni_b + d * CC, X, Y);
    k_inorm<<<256, 512, 0, stream>>>(Y, X, n1_g + d * CC, n1_b + d * CC);
    k_ffn<<<512, 256, 0, stream>>>(X, ffn_W1 + d * 128 * CC, ffn_b1 + d * 128,
                                   ffn_W2 + d * CC * 128, ffn_b2 + d * CC, Y);
    k_inorm<<<256, 512, 0, stream>>>(Y, X, n2_g + d * CC, n2_b + d * CC);
  }

  k_cls<<<64, 256, 0, stream>>>(X, cls_W, cls_b, (float*)d_out);
}